// Round 13
// baseline (479.367 us; speedup 1.0000x reference)
//
#include <hip/hip_runtime.h>

#define LLEN 8192
#define CG 16
#define NG 512    // b(16) * GROUPS(32)
#define NBLK 64   // 8 blocks per XCD -> 8 x 512 KiB = 4 MiB = one XCD L2
#define GPB (NG / NBLK)   // 8 groups per block

typedef float f32x4 __attribute__((ext_vector_type(4)));

// Persistent fused kernel: 64 blocks x 512 thr (8 waves). Each block processes
// 8 groups serially. Per group: phase 1 streams the group's 512 KiB from HBM
// (landing in the local XCD L2), computes row sums; wave 0 does softmax->taps;
// phase 2 re-reads the SAME 512 KiB (L2-hot), gates, NT-stores out (NT so the
// write stream doesn't evict x from L2). Only 8 groups in flight per XCD ->
// working set == L2 capacity.
// Occupancy shell (round-9-proven): ~120 KiB STATIC LDS (row-sum staging is
// spread across it at stride 2048 so the array is genuinely used and can't be
// shrunk) -> 1 block/CU -> 2 waves/EU -> 256-VGPR budget -> no spill.
extern "C" __global__ __launch_bounds__(512)
__attribute__((amdgpu_waves_per_eu(2, 2)))
void fused_persist(const float* __restrict__ x,  const float* __restrict__ w1,
                   const float* __restrict__ b1, const float* __restrict__ w3,
                   const float* __restrict__ b3, float* __restrict__ out) {
    __shared__ float pad[15 * 2048 + 1];   // S(row i) lives at pad[i*2048]
    __shared__ float F_lds[CG], L_lds[CG], V[49];

    const int b    = blockIdx.x;
    const int wave = threadIdx.x >> 6;     // 0..7
    const int lane = threadIdx.x & 63;

    for (int t = 0; t < GPB; ++t) {
        const int g = b * GPB + t;
        const size_t rowbase = (size_t)g * CG * LLEN;

        // ---------------- phase 1: row sums (wave w -> rows w and w+8) --------
        const f32x4* xr0 = reinterpret_cast<const f32x4*>(x + rowbase + (size_t)wave * LLEN);
        const f32x4* xr1 = reinterpret_cast<const f32x4*>(x + rowbase + (size_t)(wave + 8) * LLEN);
        float s0 = 0.f, s1 = 0.f;
        #pragma unroll
        for (int k = 0; k < 32; ++k) {
            f32x4 v0 = xr0[k * 64 + lane];
            f32x4 v1 = xr1[k * 64 + lane];
            s0 += (v0.x + v0.y) + (v0.z + v0.w);
            s1 += (v1.x + v1.y) + (v1.z + v1.w);
        }
        #pragma unroll
        for (int off = 32; off; off >>= 1) {
            s0 += __shfl_xor(s0, off, 64);
            s1 += __shfl_xor(s1, off, 64);
        }
        if (lane == 0) {
            pad[wave * 2048]       = s0;   // S[wave]
            pad[(wave + 8) * 2048] = s1;   // S[wave+8]
        }
        if (threadIdx.x < CG) {
            size_t rb = rowbase + (size_t)threadIdx.x * LLEN;
            F_lds[threadIdx.x] = x[rb];
            L_lds[threadIdx.x] = x[rb + (LLEN - 1)];
        }
        __syncthreads();

        // ---------------- prep: softmax -> collapsed taps (wave 0) ------------
        if (wave == 0) {
            const int i = lane & 15;
            const float invL = 1.0f / (float)LLEN;
            float s1a = 0.f, s2a = 0.f;
            #pragma unroll
            for (int k = 0; k < CG; ++k) {
                float Sk = pad[k * 2048];
                float Fk = F_lds[k], Lk = L_lds[k];
                s1a += w1[i * CG + k] * Sk;
                const float* w = &w3[(i * CG + k) * 3];
                s2a += w[0] * (Sk - Lk) + w[1] * Sk + w[2] * (Sk - Fk);
            }
            float m1 = s1a * invL + b1[i];
            float m2 = s2a * invL + b3[i];

            float mx1 = m1, mx2 = m2;
            #pragma unroll
            for (int off = 8; off; off >>= 1) {
                mx1 = fmaxf(mx1, __shfl_xor(mx1, off, 16));
                mx2 = fmaxf(mx2, __shfl_xor(mx2, off, 16));
            }
            float e1 = __expf(m1 - mx1), e2 = __expf(m2 - mx2);
            float d1 = e1, d2 = e2;
            #pragma unroll
            for (int off = 8; off; off >>= 1) {
                d1 += __shfl_xor(d1, off, 16);
                d2 += __shfl_xor(d2, off, 16);
            }
            float a1 = e1 / d1, a2 = e2 / d2;

            float cb = a1 * b3[i] + a2 * b1[i];
            #pragma unroll
            for (int off = 8; off; off >>= 1) cb += __shfl_xor(cb, off, 16);

            float v0 = 0.f, v1v = 0.f, v2 = 0.f;
            #pragma unroll
            for (int k = 0; k < CG; ++k) {
                float a1k = __shfl(a1, k, 16);
                float a2k = __shfl(a2, k, 16);
                const float* w = &w3[(k * CG + i) * 3];
                v0  += a1k * w[0];
                v1v += a1k * w[1] + a2k * w1[k * CG + i];
                v2  += a1k * w[2];
            }
            if (lane < 16) {
                V[i]      = v0;
                V[16 + i] = v1v;
                V[32 + i] = v2;
                if (lane == 0) V[48] = cb;
            }
        }
        __syncthreads();

        // ---------------- phase 2: gate from L2-hot x, NT store ---------------
        const float cb = V[48];
        #pragma unroll 1
        for (int rep = 0; rep < 4; ++rep) {
            const int c0 = 256 * (4 * wave + rep);
            float w0 = cb, w1a = cb, w2a = cb, w3a = cb;
            f32x4 xv[CG];
            #pragma unroll
            for (int i = 0; i < CG; ++i) {
                size_t rb = rowbase + (size_t)i * LLEN + c0;
                f32x4 v = *reinterpret_cast<const f32x4*>(x + rb + 4 * lane);
                xv[i] = v;
                float le = 0.f, re = 0.f;
                if (c0 > 0)            le = x[rb - 1];     // uniform -> scalar load, L2 hit
                if (c0 + 256 < LLEN)   re = x[rb + 256];
                float fl = __shfl_up(v.w, 1, 64);
                if (lane == 0)  fl = le;
                float fr = __shfl_down(v.x, 1, 64);
                if (lane == 63) fr = re;
                const float a0 = V[i], a1 = V[16 + i], a2 = V[32 + i];
                w0  += a0 * fl  + a1 * v.x + a2 * v.y;
                w1a += a0 * v.x + a1 * v.y + a2 * v.z;
                w2a += a0 * v.y + a1 * v.z + a2 * v.w;
                w3a += a0 * v.z + a1 * v.w + a2 * fr;
            }
            const float q0 = 1.f / (1.f + __expf(-w0));
            const float q1 = 1.f / (1.f + __expf(-w1a));
            const float q2 = 1.f / (1.f + __expf(-w2a));
            const float q3 = 1.f / (1.f + __expf(-w3a));
            #pragma unroll
            for (int i = 0; i < CG; ++i) {
                size_t rb = rowbase + (size_t)i * LLEN + c0 + 4 * lane;
                f32x4 v = xv[i];
                f32x4 o4 = { v.x * q0, v.y * q1, v.z * q2, v.w * q3 };
                __builtin_nontemporal_store(o4, reinterpret_cast<f32x4*>(out + rb));
            }
        }
        __syncthreads();   // before next iteration overwrites pad/F/L/V
    }
}

extern "C" void kernel_launch(void* const* d_in, const int* in_sizes, int n_in,
                              void* d_out, int out_size, void* d_ws, size_t ws_size,
                              hipStream_t stream) {
    const float* x  = (const float*)d_in[0];
    const float* w1 = (const float*)d_in[1];
    const float* b1 = (const float*)d_in[2];
    const float* w3 = (const float*)d_in[3];
    const float* b3 = (const float*)d_in[4];
    float* out = (float*)d_out;

    fused_persist<<<NBLK, 512, 0, stream>>>(x, w1, b1, w3, b3, out);
}

// Round 14
// 272.660 us; speedup vs baseline: 1.7581x; 1.7581x over previous
//
#include <hip/hip_runtime.h>

#define LLEN 8192
#define CG 16
#define NG 512    // b(16) * GROUPS(32)
#define NBLK 512  // 64 blocks per XCD = 8 teams x 8 members
#define THREADS 512

typedef float f32x4 __attribute__((ext_vector_type(4)));

__global__ __launch_bounds__(THREADS) void zero_flags(int* __restrict__ flags) {
    flags[threadIdx.x] = 0;     // NG == 512 == THREADS
}

// Team-cooperative persistent kernel. Team = 8 blocks on one XCD (blockIdx%8
// = XCD under round-robin dispatch). Each team processes 8 groups serially:
//   phase 1: member m partial-sums rows over cols [1024m,1024m+1024) -> wsS
//   rendezvous: device-scope flag (all 512 blocks co-resident -> spin safe)
//   prep: wave 0 softmax -> collapsed taps V (redundant per block, cheap)
//   phase 2: re-read x (L2-hot: <=8 groups in flight per XCD = 4 MiB = L2),
//            wave pair (2c,2c+1) splits rows 0-7/8-15 of chunk c, partials
//            combined via LDS; sigmoid; NT store (write stream bypasses L2).
extern "C" __global__ __launch_bounds__(THREADS)
void fused_team(const float* __restrict__ x,  const float* __restrict__ w1,
                const float* __restrict__ b1, const float* __restrict__ w3,
                const float* __restrict__ b3, float* __restrict__ out,
                float* __restrict__ wsS, int* __restrict__ flags) {
    __shared__ float V[49];             // v0[0:16) v1[16:32) v2[32:48) cb
    __shared__ float Wp[8][64][4];      // weight partials [wave][lane][tap]

    const int b    = blockIdx.x;
    const int wave = threadIdx.x >> 6;  // 0..7
    const int lane = threadIdx.x & 63;
    const int xcd  = b & 7;
    const int slot = b >> 3;            // 0..63 within XCD
    const int team = xcd * 8 + (slot >> 3);   // 0..63 global team id
    const int m    = slot & 7;          // member 0..7

    for (int t = 0; t < 8; ++t) {
        const int g = team * 8 + t;
        const size_t rowbase = (size_t)g * CG * LLEN;

        // ---------------- phase 1: partial row sums over member's col-eighth ----
        {
            const float* r0 = x + rowbase + (size_t)wave * LLEN + 1024 * m;
            const float* r1 = r0 + (size_t)8 * LLEN;
            float s0 = 0.f, s1 = 0.f;
            #pragma unroll
            for (int k = 0; k < 4; ++k) {
                f32x4 v0 = *reinterpret_cast<const f32x4*>(r0 + 256 * k + 4 * lane);
                f32x4 v1 = *reinterpret_cast<const f32x4*>(r1 + 256 * k + 4 * lane);
                s0 += (v0.x + v0.y) + (v0.z + v0.w);
                s1 += (v1.x + v1.y) + (v1.z + v1.w);
            }
            #pragma unroll
            for (int off = 32; off; off >>= 1) {
                s0 += __shfl_xor(s0, off, 64);
                s1 += __shfl_xor(s1, off, 64);
            }
            if (lane == 0) {
                __hip_atomic_store(&wsS[g * 128 + m * 16 + wave], s0,
                                   __ATOMIC_RELAXED, __HIP_MEMORY_SCOPE_AGENT);
                __hip_atomic_store(&wsS[g * 128 + m * 16 + wave + 8], s1,
                                   __ATOMIC_RELAXED, __HIP_MEMORY_SCOPE_AGENT);
            }
        }
        __syncthreads();                 // all stores drained (vmcnt0 at barrier)
        if (threadIdx.x == 0) {
            __hip_atomic_fetch_add(&flags[g], 1, __ATOMIC_ACQ_REL,
                                   __HIP_MEMORY_SCOPE_AGENT);
            while (__hip_atomic_load(&flags[g], __ATOMIC_ACQUIRE,
                                     __HIP_MEMORY_SCOPE_AGENT) < 8)
                __builtin_amdgcn_s_sleep(1);
        }
        __syncthreads();

        // ---------------- prep: softmax -> collapsed taps (wave 0) -------------
        if (wave == 0) {
            const int i = lane & 15;
            float S = 0.f;
            #pragma unroll
            for (int mm = 0; mm < 8; ++mm)
                S += __hip_atomic_load(&wsS[g * 128 + mm * 16 + i],
                                       __ATOMIC_RELAXED, __HIP_MEMORY_SCOPE_AGENT);
            float Fv = x[rowbase + (size_t)i * LLEN];
            float Lv = x[rowbase + (size_t)i * LLEN + (LLEN - 1)];
            const float invL = 1.0f / (float)LLEN;
            float s1a = 0.f, s2a = 0.f;
            #pragma unroll
            for (int k = 0; k < CG; ++k) {
                float Sk = __shfl(S,  k, 16);
                float Fk = __shfl(Fv, k, 16);
                float Lk = __shfl(Lv, k, 16);
                s1a += w1[i * CG + k] * Sk;
                const float* wp = &w3[(i * CG + k) * 3];
                s2a += wp[0] * (Sk - Lk) + wp[1] * Sk + wp[2] * (Sk - Fk);
            }
            float m1 = s1a * invL + b1[i];
            float m2 = s2a * invL + b3[i];

            float mx1 = m1, mx2 = m2;
            #pragma unroll
            for (int off = 8; off; off >>= 1) {
                mx1 = fmaxf(mx1, __shfl_xor(mx1, off, 16));
                mx2 = fmaxf(mx2, __shfl_xor(mx2, off, 16));
            }
            float e1 = __expf(m1 - mx1), e2 = __expf(m2 - mx2);
            float d1 = e1, d2 = e2;
            #pragma unroll
            for (int off = 8; off; off >>= 1) {
                d1 += __shfl_xor(d1, off, 16);
                d2 += __shfl_xor(d2, off, 16);
            }
            float a1 = e1 / d1, a2 = e2 / d2;

            float cb = a1 * b3[i] + a2 * b1[i];
            #pragma unroll
            for (int off = 8; off; off >>= 1) cb += __shfl_xor(cb, off, 16);

            float v0 = 0.f, v1v = 0.f, v2 = 0.f;
            #pragma unroll
            for (int k = 0; k < CG; ++k) {
                float a1k = __shfl(a1, k, 16);
                float a2k = __shfl(a2, k, 16);
                const float* wp = &w3[(k * CG + i) * 3];
                v0  += a1k * wp[0];
                v1v += a1k * wp[1] + a2k * w1[k * CG + i];
                v2  += a1k * wp[2];
            }
            if (lane < 16) {
                V[i]      = v0;
                V[16 + i] = v1v;
                V[32 + i] = v2;
                if (lane == 0) V[48] = cb;
            }
        }
        __syncthreads();

        // ---------------- phase 2: gate from L2-hot x, row-split wave pairs ----
        const int cidx = wave >> 1, h = wave & 1;
        const int c0 = 256 * (m * 4 + cidx);
        float w0 = 0.f, w1a = 0.f, w2a = 0.f, w3a = 0.f;
        f32x4 xv[8];
        #pragma unroll
        for (int r = 0; r < 8; ++r) {
            const int i = 8 * h + r;
            size_t rb = rowbase + (size_t)i * LLEN + c0;
            f32x4 v = *reinterpret_cast<const f32x4*>(x + rb + 4 * lane);
            xv[r] = v;
            float le = 0.f, re = 0.f;
            if (c0 > 0)            le = x[rb - 1];
            if (c0 + 256 < LLEN)   re = x[rb + 256];
            float fl = __shfl_up(v.w, 1, 64);
            if (lane == 0)  fl = le;
            float fr = __shfl_down(v.x, 1, 64);
            if (lane == 63) fr = re;
            const float a0 = V[i], a1 = V[16 + i], a2 = V[32 + i];
            w0  += a0 * fl  + a1 * v.x + a2 * v.y;
            w1a += a0 * v.x + a1 * v.y + a2 * v.z;
            w2a += a0 * v.y + a1 * v.z + a2 * v.w;
            w3a += a0 * v.z + a1 * v.w + a2 * fr;
        }
        Wp[wave][lane][0] = w0;  Wp[wave][lane][1] = w1a;
        Wp[wave][lane][2] = w2a; Wp[wave][lane][3] = w3a;
        __syncthreads();
        {
            const int pw = wave ^ 1;
            const float cbv = V[48];
            float f0 = w0  + Wp[pw][lane][0] + cbv;
            float f1 = w1a + Wp[pw][lane][1] + cbv;
            float f2 = w2a + Wp[pw][lane][2] + cbv;
            float f3 = w3a + Wp[pw][lane][3] + cbv;
            const float q0 = 1.f / (1.f + __expf(-f0));
            const float q1 = 1.f / (1.f + __expf(-f1));
            const float q2 = 1.f / (1.f + __expf(-f2));
            const float q3 = 1.f / (1.f + __expf(-f3));
            #pragma unroll
            for (int r = 0; r < 8; ++r) {
                const int i = 8 * h + r;
                size_t rb = rowbase + (size_t)i * LLEN + c0 + 4 * lane;
                f32x4 v = xv[r];
                f32x4 o4 = { v.x * q0, v.y * q1, v.z * q2, v.w * q3 };
                __builtin_nontemporal_store(o4, reinterpret_cast<f32x4*>(out + rb));
            }
        }
        __syncthreads();   // Wp protected before next group's phase 2
    }
}

extern "C" void kernel_launch(void* const* d_in, const int* in_sizes, int n_in,
                              void* d_out, int out_size, void* d_ws, size_t ws_size,
                              hipStream_t stream) {
    const float* x  = (const float*)d_in[0];
    const float* w1 = (const float*)d_in[1];
    const float* b1 = (const float*)d_in[2];
    const float* w3 = (const float*)d_in[3];
    const float* b3 = (const float*)d_in[4];
    float* out = (float*)d_out;

    int*   flags = (int*)d_ws;                          // 512 ints
    float* wsS   = (float*)((char*)d_ws + 2048);        // 512 * 128 floats

    zero_flags<<<1, THREADS, 0, stream>>>(flags);
    fused_team<<<NBLK, THREADS, 0, stream>>>(x, w1, b1, w3, b3, out, wsS, flags);
}